// Round 3
// baseline (313.618 us; speedup 1.0000x reference)
//
#include <hip/hip_runtime.h>

// Problem constants (B=8, T=4096, C=512)
#define BB 8
#define TT 4096
#define CC 512
#define MM (BB * TT)   // 32768 rows
#define SS 128         // scan chunks
#define LL 32          // steps per chunk (SS*LL == TT)

typedef short short8 __attribute__((ext_vector_type(8)));
typedef unsigned short ushort8 __attribute__((ext_vector_type(8)));
typedef float f32x4 __attribute__((ext_vector_type(4)));

__device__ __forceinline__ unsigned short f2bf(float f) {
    unsigned int u = __float_as_uint(f);
    u += 0x7FFFu + ((u >> 16) & 1u);   // RNE
    return (unsigned short)(u >> 16);
}
__device__ __forceinline__ float bf2f(unsigned short h) {
    return __uint_as_float(((unsigned int)h) << 16);
}

// async global->LDS, 16B per lane. LDS dest must be wave-uniform base + lane*16.
__device__ __forceinline__ void gl_lds16(const void* g, void* l) {
    __builtin_amdgcn_global_load_lds(
        (__attribute__((address_space(1))) void*)(unsigned long long)g,
        (__attribute__((address_space(3))) void*)(unsigned int)(unsigned long long)l,
        16, 0, 0);
}

__device__ __forceinline__ ushort8 pack8(f32x4 a, f32x4 b) {
    ushort8 r;
    r[0] = f2bf(a.x); r[1] = f2bf(a.y); r[2] = f2bf(a.z); r[3] = f2bf(a.w);
    r[4] = f2bf(b.x); r[5] = f2bf(b.y); r[6] = f2bf(b.z); r[7] = f2bf(b.w);
    return r;
}

// ---------------------------------------------------------------------------
// Kernel 1: transpose + bf16-convert the four 512x512 weights. wT[n][k]=w[k][n]
// ---------------------------------------------------------------------------
__global__ __launch_bounds__(256) void transpose_w(
    const float* __restrict__ wk, const float* __restrict__ wv,
    const float* __restrict__ wr, const float* __restrict__ wo,
    unsigned short* __restrict__ wT) {
    __shared__ float t[64][65];
    const int which = blockIdx.z;
    const float* src = (which == 0) ? wk : (which == 1) ? wv : (which == 2) ? wr : wo;
    const int k0 = blockIdx.y * 64;        // source row block
    const int n0 = blockIdx.x * 64;        // source col block
    const int r = threadIdx.x >> 6;        // 0..3
    const int c = threadIdx.x & 63;        // 0..63
#pragma unroll
    for (int p = 0; p < 16; ++p)
        t[p * 4 + r][c] = src[(size_t)(k0 + p * 4 + r) * CC + n0 + c];
    __syncthreads();
    unsigned short* dst = wT + (size_t)which * (CC * CC);
#pragma unroll
    for (int p = 0; p < 16; ++p)
        dst[(size_t)(n0 + p * 4 + r) * CC + k0 + c] = f2bf(t[c][p * 4 + r]);
}

// ---------------------------------------------------------------------------
// Kernel 2: time-shift mix for all three branches in one memory-bound pass.
// ---------------------------------------------------------------------------
__global__ __launch_bounds__(256) void mix_kvr(
    const float* __restrict__ x,
    const float* __restrict__ mixk, const float* __restrict__ mixv,
    const float* __restrict__ mixr,
    unsigned short* __restrict__ kx, unsigned short* __restrict__ vx,
    unsigned short* __restrict__ rx) {
    const int idx = blockIdx.x * 256 + threadIdx.x;   // 0 .. MM*CC/8-1
    const int row = idx >> 6;
    const int ch  = (idx & 63) * 8;
    const int t   = row & (TT - 1);
    const size_t off = (size_t)row * CC + ch;
    const float* xr = x + off;

    const f32x4 zero4 = {0.f, 0.f, 0.f, 0.f};
    const f32x4 one4  = {1.f, 1.f, 1.f, 1.f};

    f32x4 xc0 = ((const f32x4*)xr)[0];
    f32x4 xc1 = ((const f32x4*)xr)[1];
    f32x4 xp0 = zero4, xp1 = zero4;
    if (t != 0) {
        xp0 = ((const f32x4*)(xr - CC))[0];
        xp1 = ((const f32x4*)(xr - CC))[1];
    }

    f32x4 m0, m1;
    m0 = ((const f32x4*)(mixk + ch))[0];
    m1 = ((const f32x4*)(mixk + ch))[1];
    *(ushort8*)(kx + off) = pack8(xc0 * m0 + xp0 * (one4 - m0),
                                  xc1 * m1 + xp1 * (one4 - m1));
    m0 = ((const f32x4*)(mixv + ch))[0];
    m1 = ((const f32x4*)(mixv + ch))[1];
    *(ushort8*)(vx + off) = pack8(xc0 * m0 + xp0 * (one4 - m0),
                                  xc1 * m1 + xp1 * (one4 - m1));
    m0 = ((const f32x4*)(mixr + ch))[0];
    m1 = ((const f32x4*)(mixr + ch))[1];
    *(ushort8*)(rx + off) = pack8(xc0 * m0 + xp0 * (one4 - m0),
                                  xc1 * m1 + xp1 * (one4 - m1));
}

// ---------------------------------------------------------------------------
// GEMM body: 256x256 tile, 8 waves (2Mx4N, 512 thr), BK=32, 3-deep LDS,
// two 16-MFMA phases per K-tile (m201-style fine interleave):
//   [vmcnt(4); barrier]                     <- once per K-tile, never 0 mid-loop
//   stage-A(t+2); ds_read B(4)+A0..3(4); lgkmcnt(0); setprio(1) 16 MFMA (0)
//   stage-B(t+2); ds_read A4..7(4);      lgkmcnt(0); setprio(1) 16 MFMA (0)
// Hazards: reads of buf b are lgkm-drained before each wave reaches the next
// barrier; the stage into buf (t+3)%3==b issues only after that barrier.
// vmcnt(4) leaves exactly tile t+1's 4 loads in flight => tile t landed.
// LDS layout identical to the verified round-2 one: [256][32] bf16, 16B group
// g stored at slot g ^ ((row>>1)&3)  -> measured 0 bank conflicts.
// ---------------------------------------------------------------------------
template <bool F32OUT>
__device__ __forceinline__ void gemm_body(
    const unsigned short* __restrict__ A,
    const unsigned short* __restrict__ Bw,
    void* __restrict__ OutP, const int sig,
    const int pm, const int pn) {
    __shared__ unsigned short As[3][256 * 32];   // 3 x 16 KiB
    __shared__ unsigned short Bs[3][256 * 32];   // 3 x 16 KiB

    const int tid = threadIdx.x;                 // 0..511
    // staging: seg tid covers tile-row (tid>>2) (+128 for 2nd load), 16B group
    // (tid&3); source group pre-swizzled: cg = (tid&3) ^ ((row>>1)&3).
    const int cg = (tid & 3) ^ ((tid >> 3) & 3);
    const unsigned short* agA = A  + (size_t)(pm * 256 + (tid >> 2)) * CC + cg * 8;
    const unsigned short* agB = Bw + (size_t)(pn * 256 + (tid >> 2)) * CC + cg * 8;

    const int wid = tid >> 6;                    // 0..7
    const int wr = wid >> 2, wc = wid & 3;       // 2 x 4 wave grid
    const int lane = tid & 63;
    const int q = lane >> 4, l16 = lane & 15;
    const int sw = (q ^ ((l16 >> 1) & 3)) * 8;   // reader-side swizzle

    const int aro = (wr * 128 + l16) * 32 + sw;  // + i*512 (i=0..7)
    const int bro = (wc * 64 + l16) * 32 + sw;   // + j*512 (j=0..3)

    f32x4 acc[8][4];
#pragma unroll
    for (int i = 0; i < 8; i++)
#pragma unroll
        for (int j = 0; j < 4; j++) acc[i][j] = (f32x4){0.f, 0.f, 0.f, 0.f};

#define STG_A(bi_, ke) do {                                                   \
    gl_lds16(agA + (ke), &As[bi_][tid * 8]);                                  \
    gl_lds16(agA + (size_t)128 * CC + (ke), &As[bi_][4096 + tid * 8]);        \
} while (0)
#define STG_B(bi_, ke) do {                                                   \
    gl_lds16(agB + (ke), &Bs[bi_][tid * 8]);                                  \
    gl_lds16(agB + (size_t)128 * CC + (ke), &Bs[bi_][4096 + tid * 8]);        \
} while (0)

    STG_A(0, 0);  STG_B(0, 0);     // tile 0 -> buf 0
    STG_A(1, 32); STG_B(1, 32);    // tile 1 -> buf 1

    short8 bfr[4], af[4];

#define KT_PHASES(bi_, DO_STAGE, ke) do {                                     \
    const int bi2_ = (bi_) + 2 >= 3 ? (bi_) - 1 : (bi_) + 2;                  \
    if (DO_STAGE) STG_A(bi2_, ke);                                            \
    _Pragma("unroll")                                                         \
    for (int j = 0; j < 4; ++j)                                               \
        bfr[j] = *(const short8*)&Bs[bi_][bro + j * 512];                     \
    _Pragma("unroll")                                                         \
    for (int i = 0; i < 4; ++i)                                               \
        af[i] = *(const short8*)&As[bi_][aro + i * 512];                      \
    asm volatile("s_waitcnt lgkmcnt(0)" ::: "memory");                        \
    __builtin_amdgcn_s_setprio(1);                                            \
    _Pragma("unroll")                                                         \
    for (int i = 0; i < 4; ++i)                                               \
        _Pragma("unroll")                                                     \
        for (int j = 0; j < 4; ++j)                                           \
            acc[i][j] = __builtin_amdgcn_mfma_f32_16x16x32_bf16(              \
                af[i], bfr[j], acc[i][j], 0, 0, 0);                           \
    __builtin_amdgcn_s_setprio(0);                                            \
    if (DO_STAGE) STG_B(bi2_, ke);                                            \
    _Pragma("unroll")                                                         \
    for (int i = 0; i < 4; ++i)                                               \
        af[i] = *(const short8*)&As[bi_][aro + 2048 + i * 512];               \
    asm volatile("s_waitcnt lgkmcnt(0)" ::: "memory");                        \
    __builtin_amdgcn_s_setprio(1);                                            \
    _Pragma("unroll")                                                         \
    for (int i = 0; i < 4; ++i)                                               \
        _Pragma("unroll")                                                     \
        for (int j = 0; j < 4; ++j)                                           \
            acc[4 + i][j] = __builtin_amdgcn_mfma_f32_16x16x32_bf16(          \
                af[i], bfr[j], acc[4 + i][j], 0, 0, 0);                       \
    __builtin_amdgcn_s_setprio(0);                                            \
} while (0)

    int bi = 0, ks = 64;
#pragma unroll 1
    for (int t = 0; t < 15; ++t) {
        asm volatile("s_waitcnt vmcnt(4)" ::: "memory");
        __builtin_amdgcn_s_barrier();
        KT_PHASES(bi, (t < 14), ks);
        ks += 32;
        bi = (bi + 1 == 3) ? 0 : bi + 1;
    }
    asm volatile("s_waitcnt vmcnt(0)" ::: "memory");
    __builtin_amdgcn_s_barrier();
    KT_PHASES(bi, false, 0);

#undef KT_PHASES
#undef STG_A
#undef STG_B

    // epilogue: row = pm*256 + wr*128 + i*16 + q*4 + ii
    //           col = pn*256 + wc*64  + j*16 + l16
    const size_t rb = (size_t)pm * 256 + wr * 128;
    const int nb = pn * 256 + wc * 64;
    if constexpr (F32OUT) {
        float* Out = (float*)OutP;
#pragma unroll
        for (int i = 0; i < 8; i++)
#pragma unroll
            for (int j = 0; j < 4; j++)
#pragma unroll
                for (int ii = 0; ii < 4; ii++) {
                    const int m = i * 16 + q * 4 + ii;
                    const int n = nb + j * 16 + l16;
                    Out[(rb + m) * CC + n] = acc[i][j][ii];
                }
    } else {
        unsigned short* Out = (unsigned short*)OutP;
#pragma unroll
        for (int i = 0; i < 8; i++)
#pragma unroll
            for (int j = 0; j < 4; j++)
#pragma unroll
                for (int ii = 0; ii < 4; ii++) {
                    const int m = i * 16 + q * 4 + ii;
                    const int n = nb + j * 16 + l16;
                    float val = acc[i][j][ii];
                    if (sig) val = 1.0f / (1.0f + __expf(-val));
                    Out[(rb + m) * CC + n] = f2bf(val);
                }
    }
}

// ---------------------------------------------------------------------------
// Kernel 3: all three branch GEMMs in ONE dispatch. 768 blocks = 3 rounds of
// 256 CUs, 1 block/CU (96 KiB LDS). XCD swizzle keeps the pn-pair of each
// A-panel on the same XCD (768 % 8 == 0, bijective).
// ---------------------------------------------------------------------------
__global__ __launch_bounds__(512, 2) void gemm_kvr3(
    const unsigned short* __restrict__ wT,
    const unsigned short* __restrict__ A0, const unsigned short* __restrict__ A1,
    const unsigned short* __restrict__ A2,
    unsigned short* __restrict__ O0, unsigned short* __restrict__ O1,
    unsigned short* __restrict__ O2) {
    const int lin = blockIdx.x;                  // 0..767
    const int wg = (lin & 7) * 96 + (lin >> 3);  // XCD-contiguous
    const int z = wg >> 8;                       // 0..2
    const int r = wg & 255;
    const int pm = r >> 1, pn = r & 1;
    const unsigned short* A = (z == 0) ? A0 : (z == 1) ? A1 : A2;
    unsigned short* O = (z == 0) ? O0 : (z == 1) ? O1 : O2;
    gemm_body<false>(A, wT + (size_t)z * (CC * CC), O, z == 2, pm, pn);
}

// ---------------------------------------------------------------------------
// Kernel 4: out = z @ wo (fp32 output), same pipeline. 256 blocks = 1 round.
// ---------------------------------------------------------------------------
__global__ __launch_bounds__(512, 2) void gemm_out(
    const unsigned short* __restrict__ zb, const unsigned short* __restrict__ woT,
    float* __restrict__ out) {
    const int lin = blockIdx.x;                  // 0..255
    const int wg = (lin & 7) * 32 + (lin >> 3);
    gemm_body<true>(zb, woT, out, 0, wg >> 1, wg & 1);
}

// ---------------------------------------------------------------------------
// WKV chunked parallel scan (unchanged).
// ---------------------------------------------------------------------------
__global__ __launch_bounds__(256) void wkv_part1(
    const unsigned short* __restrict__ kb, const unsigned short* __restrict__ vb,
    const float* __restrict__ sd,
    float* __restrict__ sp_, float* __restrict__ sq_, float* __restrict__ so_) {
    const int idx = blockIdx.x * 256 + threadIdx.x;
    const int c = idx & (CC - 1);
    const int b = (idx >> 9) & (BB - 1);
    const int s = idx >> 12;
    const float w = sd[c] * (1.0f / (float)TT);
    const size_t base = ((size_t)b * TT + (size_t)s * LL) * CC + c;
    const unsigned short* kp = kb + base;
    const unsigned short* vp = vb + base;

    float p = 0.f, q = 0.f, o = -1e38f;
#pragma unroll 8
    for (int i = 0; i < LL; ++i) {
        const float kt = bf2f(kp[(size_t)i * CC]);
        const float vt = bf2f(vp[(size_t)i * CC]);
        const float no2 = fmaxf(w + o, kt);
        const float A2  = __expf(w + o - no2);
        const float B2  = __expf(kt - no2);
        p = A2 * p + B2 * vt;
        q = A2 * q + B2;
        o = no2;
    }
    sp_[idx] = p; sq_[idx] = q; so_[idx] = o;
}

__global__ __launch_bounds__(256) void wkv_part2(
    const float* __restrict__ sd,
    float* __restrict__ sp_, float* __restrict__ sq_, float* __restrict__ so_) {
    const int idx = blockIdx.x * 256 + threadIdx.x;
    const int c = idx & (CC - 1);
    const float wL = sd[c] * ((float)LL / (float)TT);

    float p = 0.f, q = 0.f, o = -1e38f;
    float lp = sp_[idx], lq = sq_[idx], lo = so_[idx];
    for (int s = 0; s < SS; ++s) {
        const int off = s * (BB * CC) + idx;
        float nlp = 0.f, nlq = 0.f, nlo = 0.f;
        if (s + 1 < SS) {
            nlp = sp_[off + BB * CC];
            nlq = sq_[off + BB * CC];
            nlo = so_[off + BB * CC];
        }
        sp_[off] = p; sq_[off] = q; so_[off] = o;
        const float no = fmaxf(o + wL, lo);
        const float A  = __expf(o + wL - no);
        const float Bc = __expf(lo - no);
        p = A * p + Bc * lp;
        q = A * q + Bc * lq;
        o = no;
        lp = nlp; lq = nlq; lo = nlo;
    }
}

__global__ __launch_bounds__(256) void wkv_part3(
    const unsigned short* __restrict__ kb, const unsigned short* __restrict__ vb,
    const unsigned short* __restrict__ srb,
    const float* __restrict__ sd, const float* __restrict__ sf,
    const float* __restrict__ sp_, const float* __restrict__ sq_,
    const float* __restrict__ so_,
    unsigned short* __restrict__ zb) {
    const int idx = blockIdx.x * 256 + threadIdx.x;
    const int c = idx & (CC - 1);
    const int b = (idx >> 9) & (BB - 1);
    const int s = idx >> 12;
    const float w = sd[c] * (1.0f / (float)TT);
    const float u = sf[c] * (1.0f / (float)TT);
    const size_t base = ((size_t)b * TT + (size_t)s * LL) * CC + c;
    const unsigned short* kp = kb + base;
    const unsigned short* vp = vb + base;
    const unsigned short* sp = srb + base;
    unsigned short* zp = zb + base;

    float p = sp_[idx], q = sq_[idx], o = so_[idx];
#pragma unroll 4
    for (int i = 0; i < LL; ++i) {
        const float kt = bf2f(kp[(size_t)i * CC]);
        const float vt = bf2f(vp[(size_t)i * CC]);
        const float sr = bf2f(sp[(size_t)i * CC]);

        const float no = fmaxf(o, u + kt);
        const float A  = __expf(o - no);
        const float Bt = __expf(u + kt - no);
        const float y  = (A * p + Bt * vt) / (A * q + Bt);
        zp[(size_t)i * CC] = f2bf(sr * y);

        const float no2 = fmaxf(w + o, kt);
        const float A2  = __expf(w + o - no2);
        const float B2  = __expf(kt - no2);
        p = A2 * p + B2 * vt;
        q = A2 * q + B2;
        o = no2;
    }
}

// ---------------------------------------------------------------------------
extern "C" void kernel_launch(void* const* d_in, const int* in_sizes, int n_in,
                              void* d_out, int out_size, void* d_ws, size_t ws_size,
                              hipStream_t stream) {
    const float* x  = (const float*)d_in[0];
    const float* sd = (const float*)d_in[1];
    const float* sf = (const float*)d_in[2];
    const float* mk = (const float*)d_in[3];
    const float* mv = (const float*)d_in[4];
    const float* mr = (const float*)d_in[5];
    const float* wk = (const float*)d_in[6];
    const float* wv = (const float*)d_in[7];
    const float* wr = (const float*)d_in[8];
    const float* wo = (const float*)d_in[9];
    float* out = (float*)d_out;

    // ws layout (168 MiB total; ws ceiling is in [194,200) MiB):
    //   wT     bf16 [4][512][512]  2 MiB
    //   b1..b5 bf16 [M][C]         5 x 32 MiB
    //   sp/sq/so fp32 [S][B][C]    3 x 2 MiB
    //
    // Rotation (one fused GEMM dispatch -> all 3 outputs need fresh buffers;
    // sigmoid(r) goes to d_out used as bf16 scratch, overwritten by gemm_out):
    //   mix:  x -> b1 (xk), b2 (xv), b3 (xr)
    //   gemm: b1@wk -> b4 (k) ; b2@wv -> b5 (v) ; b3@wr -> srS=d_out (sr)
    //   wkv:  (b4, b5, srS) -> b1 (z)
    //   out:  b1 @ wo -> out (fp32, overwrites srS region)
    char* ws = (char*)d_ws;
    unsigned short* wT = (unsigned short*)ws;
    unsigned short* b1 = wT + (size_t)4 * CC * CC;
    unsigned short* b2 = b1 + (size_t)MM * CC;
    unsigned short* b3 = b2 + (size_t)MM * CC;
    unsigned short* b4 = b3 + (size_t)MM * CC;
    unsigned short* b5 = b4 + (size_t)MM * CC;
    float* sp_ = (float*)(b5 + (size_t)MM * CC);
    float* sq_ = sp_ + (size_t)SS * BB * CC;
    float* so_ = sq_ + (size_t)SS * BB * CC;
    unsigned short* woT = wT + (size_t)3 * CC * CC;
    unsigned short* srS = (unsigned short*)d_out;   // bf16 scratch inside out

    transpose_w<<<dim3(8, 8, 4), 256, 0, stream>>>(wk, wv, wr, wo, wT);

    mix_kvr<<<dim3((MM * CC / 8) / 256), 256, 0, stream>>>(
        x, mk, mv, mr, b1, b2, b3);

    gemm_kvr3<<<dim3(768), 512, 0, stream>>>(wT, b1, b2, b3, b4, b5, srS);

    wkv_part1<<<dim3((SS * BB * CC) / 256), 256, 0, stream>>>(b4, b5, sd, sp_, sq_, so_);
    wkv_part2<<<dim3((BB * CC) / 256), 256, 0, stream>>>(sd, sp_, sq_, so_);
    wkv_part3<<<dim3((SS * BB * CC) / 256), 256, 0, stream>>>(
        b4, b5, srS, sd, sf, sp_, sq_, so_, b1);

    gemm_out<<<dim3(256), 512, 0, stream>>>(b1, woT, out);
}

// Round 4
// 299.802 us; speedup vs baseline: 1.0461x; 1.0461x over previous
//
#include <hip/hip_runtime.h>

// Problem constants (B=8, T=4096, C=512)
#define BB 8
#define TT 4096
#define CC 512
#define MM (BB * TT)   // 32768 rows
#define SS 128         // scan chunks
#define LL 32          // steps per chunk (SS*LL == TT)

typedef short short8 __attribute__((ext_vector_type(8)));
typedef unsigned short ushort8 __attribute__((ext_vector_type(8)));
typedef float f32x4 __attribute__((ext_vector_type(4)));

__device__ __forceinline__ unsigned short f2bf(float f) {
    unsigned int u = __float_as_uint(f);
    u += 0x7FFFu + ((u >> 16) & 1u);   // RNE
    return (unsigned short)(u >> 16);
}
__device__ __forceinline__ float bf2f(unsigned short h) {
    return __uint_as_float(((unsigned int)h) << 16);
}

// async global->LDS, 16B per lane. LDS dest must be wave-uniform base + lane*16.
__device__ __forceinline__ void gl_lds16(const void* g, void* l) {
    __builtin_amdgcn_global_load_lds(
        (__attribute__((address_space(1))) void*)(unsigned long long)g,
        (__attribute__((address_space(3))) void*)(unsigned int)(unsigned long long)l,
        16, 0, 0);
}

__device__ __forceinline__ ushort8 pack8(f32x4 a, f32x4 b) {
    ushort8 r;
    r[0] = f2bf(a.x); r[1] = f2bf(a.y); r[2] = f2bf(a.z); r[3] = f2bf(a.w);
    r[4] = f2bf(b.x); r[5] = f2bf(b.y); r[6] = f2bf(b.z); r[7] = f2bf(b.w);
    return r;
}

// ---------------------------------------------------------------------------
// Kernel 1: prep = weight transpose (blocks 0..255) + time-shift mix
// (blocks 256..8447) fused into one dispatch to cut a launch gap.
// ---------------------------------------------------------------------------
__global__ __launch_bounds__(256) void prep(
    const float* __restrict__ x,
    const float* __restrict__ mixk, const float* __restrict__ mixv,
    const float* __restrict__ mixr,
    const float* __restrict__ wk, const float* __restrict__ wv,
    const float* __restrict__ wr, const float* __restrict__ wo,
    unsigned short* __restrict__ wT,
    unsigned short* __restrict__ kx, unsigned short* __restrict__ vx,
    unsigned short* __restrict__ rx) {
    __shared__ float t[64][65];
    if (blockIdx.x < 256) {
        // ---- weight transpose: wT[n][k] = bf16(w[k][n]), LDS 64x64 tile ----
        const int bid = blockIdx.x;
        const int which = bid >> 6;
        const int rem = bid & 63;
        const int k0 = (rem >> 3) * 64;       // source row block
        const int n0 = (rem & 7) * 64;        // source col block
        const float* src = (which == 0) ? wk : (which == 1) ? wv
                         : (which == 2) ? wr : wo;
        const int r = threadIdx.x >> 6;       // 0..3
        const int c = threadIdx.x & 63;       // 0..63
#pragma unroll
        for (int p = 0; p < 16; ++p)
            t[p * 4 + r][c] = src[(size_t)(k0 + p * 4 + r) * CC + n0 + c];
        __syncthreads();
        unsigned short* dst = wT + (size_t)which * (CC * CC);
#pragma unroll
        for (int p = 0; p < 16; ++p)
            dst[(size_t)(n0 + p * 4 + r) * CC + k0 + c] = f2bf(t[c][p * 4 + r]);
        return;
    }
    // ---- time-shift mix for all three branches, one memory pass ----
    const int idx = (blockIdx.x - 256) * 256 + threadIdx.x;   // 0 .. MM*CC/8-1
    const int row = idx >> 6;
    const int ch  = (idx & 63) * 8;
    const int tt  = row & (TT - 1);
    const size_t off = (size_t)row * CC + ch;
    const float* xr = x + off;

    const f32x4 zero4 = {0.f, 0.f, 0.f, 0.f};
    const f32x4 one4  = {1.f, 1.f, 1.f, 1.f};

    f32x4 xc0 = ((const f32x4*)xr)[0];
    f32x4 xc1 = ((const f32x4*)xr)[1];
    f32x4 xp0 = zero4, xp1 = zero4;
    if (tt != 0) {
        xp0 = ((const f32x4*)(xr - CC))[0];
        xp1 = ((const f32x4*)(xr - CC))[1];
    }

    f32x4 m0, m1;
    m0 = ((const f32x4*)(mixk + ch))[0];
    m1 = ((const f32x4*)(mixk + ch))[1];
    *(ushort8*)(kx + off) = pack8(xc0 * m0 + xp0 * (one4 - m0),
                                  xc1 * m1 + xp1 * (one4 - m1));
    m0 = ((const f32x4*)(mixv + ch))[0];
    m1 = ((const f32x4*)(mixv + ch))[1];
    *(ushort8*)(vx + off) = pack8(xc0 * m0 + xp0 * (one4 - m0),
                                  xc1 * m1 + xp1 * (one4 - m1));
    m0 = ((const f32x4*)(mixr + ch))[0];
    m1 = ((const f32x4*)(mixr + ch))[1];
    *(ushort8*)(rx + off) = pack8(xc0 * m0 + xp0 * (one4 - m0),
                                  xc1 * m1 + xp1 * (one4 - m1));
}

// ---------------------------------------------------------------------------
// GEMM body: 128x256 tile, 3-deep LDS pipeline, counted vmcnt, raw barriers.
// EXACT round-2 structure (measured: 75.5 us for 3 GEMMs, 0 bank conflicts,
// 2 blocks/CU -> cross-block MFMA/stage overlap).
// Per K-step kt: STAGE(kt+2) | vmcnt(12) | barrier | ds_read buf[kt%3] |
//                lgkmcnt(0) | barrier | setprio(1) 32xMFMA setprio(0)
// vmcnt(12) = 2 stages x 6 loads in flight => own stage(kt) landed; barrier-A
// makes that true for ALL waves. lgkmcnt(0)+barrier-B retires all reads of
// buf[kt%3] before any wave's next-iter STAGE overwrites it.
// LDS swizzle: 16B group g of row r at slot g ^ ((r>>1)&3) -> 2-way max.
// ---------------------------------------------------------------------------
template <bool F32OUT>
__device__ __forceinline__ void gemm_body(
    const unsigned short* __restrict__ A,
    const unsigned short* __restrict__ Bw,
    void* __restrict__ OutP, const int sig,
    const int pm, const int pn) {
    __shared__ unsigned short As[3][128 * 32];    // 3 x  8 KiB
    __shared__ unsigned short Bs[3][256 * 32];    // 3 x 16 KiB

    const int tid = threadIdx.x;
    const int ar = tid >> 2;                        // 0..63
    const int cg = (tid & 3) ^ ((tid >> 3) & 3);
    const unsigned short* agA = A  + (size_t)(pm * 128 + ar) * CC + cg * 8;
    const unsigned short* agB = Bw + (size_t)(pn * 256 + ar) * CC + cg * 8;

    const int w = tid >> 6, lane = tid & 63;
    const int wr = w >> 1, wc = w & 1;
    const int q = lane >> 4, l16 = lane & 15;
    const int sw = (q ^ ((l16 >> 1) & 3)) * 8;      // reader-side swizzle

    f32x4 acc[4][8];
#pragma unroll
    for (int i = 0; i < 4; i++)
#pragma unroll
        for (int j = 0; j < 8; j++) acc[i][j] = (f32x4){0.f, 0.f, 0.f, 0.f};

#define STG(bi, k0) do {                                                        \
    gl_lds16(agA + (k0), &As[bi][tid * 8]);                                     \
    gl_lds16(agA + (size_t)64 * CC + (k0), &As[bi][(256 + tid) * 8]);           \
    gl_lds16(agB + (k0),                    &Bs[bi][(0 * 256 + tid) * 8]);      \
    gl_lds16(agB + (size_t)64  * CC + (k0), &Bs[bi][(1 * 256 + tid) * 8]);      \
    gl_lds16(agB + (size_t)128 * CC + (k0), &Bs[bi][(2 * 256 + tid) * 8]);      \
    gl_lds16(agB + (size_t)192 * CC + (k0), &Bs[bi][(3 * 256 + tid) * 8]);      \
} while (0)

    STG(0, 0);
    STG(1, 32);

#pragma unroll
    for (int kt = 0; kt < 16; ++kt) {
        const int bi = kt % 3;                      // compile-time (unrolled)
        if (kt + 2 < 16) STG((kt + 2) % 3, (kt + 2) * 32);

        if (kt < 14)       asm volatile("s_waitcnt vmcnt(12)" ::: "memory");
        else if (kt == 14) asm volatile("s_waitcnt vmcnt(6)" ::: "memory");
        else               asm volatile("s_waitcnt vmcnt(0)" ::: "memory");
        __builtin_amdgcn_s_barrier();               // buf[bi] ready for all

        short8 a[4], b[8];
#pragma unroll
        for (int i = 0; i < 4; i++)
            a[i] = *(const short8*)&As[bi][(wr * 64 + i * 16 + l16) * 32 + sw];
#pragma unroll
        for (int j = 0; j < 8; j++)
            b[j] = *(const short8*)&Bs[bi][(wc * 128 + j * 16 + l16) * 32 + sw];
        asm volatile("s_waitcnt lgkmcnt(0)" ::: "memory");
        __builtin_amdgcn_s_barrier();               // reads retired for all

        __builtin_amdgcn_s_setprio(1);
#pragma unroll
        for (int i = 0; i < 4; i++)
#pragma unroll
            for (int j = 0; j < 8; j++)
                acc[i][j] = __builtin_amdgcn_mfma_f32_16x16x32_bf16(a[i], b[j], acc[i][j], 0, 0, 0);
        __builtin_amdgcn_s_setprio(0);
    }
#undef STG

    // epilogue: row = wr*64 + i*16 + q*4 + ii, col = pn*256 + wc*128 + j*16 + l16
    const size_t rb = (size_t)pm * 128 + wr * 64;
    const int nb = pn * 256 + wc * 128;
    if constexpr (F32OUT) {
        float* Out = (float*)OutP;
#pragma unroll
        for (int i = 0; i < 4; i++)
#pragma unroll
            for (int j = 0; j < 8; j++)
#pragma unroll
                for (int ii = 0; ii < 4; ii++) {
                    const int m = i * 16 + q * 4 + ii;
                    const int n = nb + j * 16 + l16;
                    Out[(rb + m) * CC + n] = acc[i][j][ii];
                }
    } else {
        unsigned short* Out = (unsigned short*)OutP;
#pragma unroll
        for (int i = 0; i < 4; i++)
#pragma unroll
            for (int j = 0; j < 8; j++)
#pragma unroll
                for (int ii = 0; ii < 4; ii++) {
                    const int m = i * 16 + q * 4 + ii;
                    const int n = nb + j * 16 + l16;
                    float val = acc[i][j][ii];
                    if (sig) val = 1.0f / (1.0f + __expf(-val));
                    Out[(rb + m) * CC + n] = f2bf(val);
                }
    }
}

// ---------------------------------------------------------------------------
// Kernel 2: all three branch GEMMs in ONE dispatch (round-2 proven).
// ---------------------------------------------------------------------------
__global__ __launch_bounds__(256, 2) void gemm_kvr3(
    const unsigned short* __restrict__ wT,
    const unsigned short* __restrict__ A0, const unsigned short* __restrict__ A1,
    const unsigned short* __restrict__ A2,
    unsigned short* __restrict__ O0, unsigned short* __restrict__ O1,
    unsigned short* __restrict__ O2) {
    const int z = blockIdx.y;
    const int lin = blockIdx.x;
    const int wg = (lin & 7) * 64 + (lin >> 3);
    const int pm = wg >> 1, pn = wg & 1;
    const unsigned short* A = (z == 0) ? A0 : (z == 1) ? A1 : A2;
    unsigned short* O = (z == 0) ? O0 : (z == 1) ? O1 : O2;
    gemm_body<false>(A, wT + (size_t)z * (CC * CC), O, z == 2, pm, pn);
}

// ---------------------------------------------------------------------------
// Kernel 3: out = z @ wo (fp32 output), same pipeline.
// ---------------------------------------------------------------------------
__global__ __launch_bounds__(256, 2) void gemm_out(
    const unsigned short* __restrict__ zb, const unsigned short* __restrict__ woT,
    float* __restrict__ out) {
    const int lin = blockIdx.x;
    const int wg = (lin & 7) * 64 + (lin >> 3);
    gemm_body<true>(zb, woT, out, 0, wg >> 1, wg & 1);
}

// ---------------------------------------------------------------------------
// WKV chunked parallel scan. part1 (per-chunk local states) unchanged.
// ---------------------------------------------------------------------------
__global__ __launch_bounds__(256) void wkv_part1(
    const unsigned short* __restrict__ kb, const unsigned short* __restrict__ vb,
    const float* __restrict__ sd,
    float* __restrict__ sp_, float* __restrict__ sq_, float* __restrict__ so_) {
    const int idx = blockIdx.x * 256 + threadIdx.x;
    const int c = idx & (CC - 1);
    const int b = (idx >> 9) & (BB - 1);
    const int s = idx >> 12;
    const float w = sd[c] * (1.0f / (float)TT);
    const size_t base = ((size_t)b * TT + (size_t)s * LL) * CC + c;
    const unsigned short* kp = kb + base;
    const unsigned short* vp = vb + base;

    float p = 0.f, q = 0.f, o = -1e38f;
#pragma unroll 8
    for (int i = 0; i < LL; ++i) {
        const float kt = bf2f(kp[(size_t)i * CC]);
        const float vt = bf2f(vp[(size_t)i * CC]);
        const float no2 = fmaxf(w + o, kt);
        const float A2  = __expf(w + o - no2);
        const float B2  = __expf(kt - no2);
        p = A2 * p + B2 * vt;
        q = A2 * q + B2;
        o = no2;
    }
    sp_[idx] = p; sq_[idx] = q; so_[idx] = o;
}

// ---------------------------------------------------------------------------
// wkv_scan: REPLACES the serial wkv_part2 (128 dependent global-memory
// iterations, 16 blocks) with a Hillis-Steele scan over the 128 chunk
// aggregates, in LDS, per (b,c) group. Combine is associative with a
// per-step decay wL*2^d (right segment at step d spans 2^d chunks).
// In-place on sp_/sq_/so_; exclusive output (state BEFORE chunk s).
// ---------------------------------------------------------------------------
__global__ __launch_bounds__(256) void wkv_scan(
    const float* __restrict__ sd,
    float* __restrict__ sp_, float* __restrict__ sq_, float* __restrict__ so_) {
    __shared__ float P[2][128], Q[2][128], O[2][128];
    const int gsub = threadIdx.x >> 7;        // 0..1 (two groups per block)
    const int s    = threadIdx.x & 127;       // chunk index
    const int g    = blockIdx.x * 2 + gsub;   // 0..4095 = b*CC + c
    const int c    = g & (CC - 1);
    const float wL = sd[c] * ((float)LL / (float)TT);
    const int stride = BB * CC;               // 4096

    float p = sp_[s * stride + g];
    float q = sq_[s * stride + g];
    float o = so_[s * stride + g];
    P[gsub][s] = p; Q[gsub][s] = q; O[gsub][s] = o;

    float dec = wL;                            // wL * 2^d
#pragma unroll
    for (int d = 0; d < 7; ++d) {
        const int off = 1 << d;
        __syncthreads();
        float pl = 0.f, ql = 0.f, ol = -1e38f;
        if (s >= off) {
            pl = P[gsub][s - off]; ql = Q[gsub][s - off]; ol = O[gsub][s - off];
        }
        __syncthreads();
        if (s >= off) {
            // append own (right, 2^d chunks) after left aggregate
            const float no = fmaxf(ol + dec, o);
            const float Al = __expf(ol + dec - no);
            const float Bc = __expf(o - no);
            p = Al * pl + Bc * p;
            q = Al * ql + Bc * q;
            o = no;
            P[gsub][s] = p; Q[gsub][s] = q; O[gsub][s] = o;
        }
        dec += dec;
    }
    __syncthreads();
    // exclusive: state before chunk s (identity for s==0)
    float ep = 0.f, eq = 0.f, eo = -1e38f;
    if (s > 0) { ep = P[gsub][s - 1]; eq = Q[gsub][s - 1]; eo = O[gsub][s - 1]; }
    sp_[s * stride + g] = ep;
    sq_[s * stride + g] = eq;
    so_[s * stride + g] = eo;
}

__global__ __launch_bounds__(256) void wkv_part3(
    const unsigned short* __restrict__ kb, const unsigned short* __restrict__ vb,
    const unsigned short* __restrict__ srb,
    const float* __restrict__ sd, const float* __restrict__ sf,
    const float* __restrict__ sp_, const float* __restrict__ sq_,
    const float* __restrict__ so_,
    unsigned short* __restrict__ zb) {
    const int idx = blockIdx.x * 256 + threadIdx.x;
    const int c = idx & (CC - 1);
    const int b = (idx >> 9) & (BB - 1);
    const int s = idx >> 12;
    const float w = sd[c] * (1.0f / (float)TT);
    const float u = sf[c] * (1.0f / (float)TT);
    const size_t base = ((size_t)b * TT + (size_t)s * LL) * CC + c;
    const unsigned short* kp = kb + base;
    const unsigned short* vp = vb + base;
    const unsigned short* sp = srb + base;
    unsigned short* zp = zb + base;

    float p = sp_[idx], q = sq_[idx], o = so_[idx];
#pragma unroll 4
    for (int i = 0; i < LL; ++i) {
        const float kt = bf2f(kp[(size_t)i * CC]);
        const float vt = bf2f(vp[(size_t)i * CC]);
        const float sr = bf2f(sp[(size_t)i * CC]);

        const float no = fmaxf(o, u + kt);
        const float A  = __expf(o - no);
        const float Bt = __expf(u + kt - no);
        const float y  = (A * p + Bt * vt) / (A * q + Bt);
        zp[(size_t)i * CC] = f2bf(sr * y);

        const float no2 = fmaxf(w + o, kt);
        const float A2  = __expf(w + o - no2);
        const float B2  = __expf(kt - no2);
        p = A2 * p + B2 * vt;
        q = A2 * q + B2;
        o = no2;
    }
}

// ---------------------------------------------------------------------------
extern "C" void kernel_launch(void* const* d_in, const int* in_sizes, int n_in,
                              void* d_out, int out_size, void* d_ws, size_t ws_size,
                              hipStream_t stream) {
    const float* x  = (const float*)d_in[0];
    const float* sd = (const float*)d_in[1];
    const float* sf = (const float*)d_in[2];
    const float* mk = (const float*)d_in[3];
    const float* mv = (const float*)d_in[4];
    const float* mr = (const float*)d_in[5];
    const float* wk = (const float*)d_in[6];
    const float* wv = (const float*)d_in[7];
    const float* wr = (const float*)d_in[8];
    const float* wo = (const float*)d_in[9];
    float* out = (float*)d_out;

    // ws layout (168 MiB total; ws ceiling is in [194,200) MiB):
    //   wT     bf16 [4][512][512]  2 MiB
    //   b1..b5 bf16 [M][C]         5 x 32 MiB
    //   sp/sq/so fp32 [S][B][C]    3 x 2 MiB
    //
    // Rotation (one fused GEMM dispatch -> all 3 outputs need fresh buffers;
    // sigmoid(r) goes to d_out used as bf16 scratch, overwritten by gemm_out):
    //   prep: x -> b1 (xk), b2 (xv), b3 (xr); weights -> wT
    //   gemm: b1@wk -> b4 (k) ; b2@wv -> b5 (v) ; b3@wr -> srS=d_out (sr)
    //   wkv:  (b4, b5, srS) -> b1 (z)
    //   out:  b1 @ wo -> out (fp32, overwrites srS region)
    char* ws = (char*)d_ws;
    unsigned short* wT = (unsigned short*)ws;
    unsigned short* b1 = wT + (size_t)4 * CC * CC;
    unsigned short* b2 = b1 + (size_t)MM * CC;
    unsigned short* b3 = b2 + (size_t)MM * CC;
    unsigned short* b4 = b3 + (size_t)MM * CC;
    unsigned short* b5 = b4 + (size_t)MM * CC;
    float* sp_ = (float*)(b5 + (size_t)MM * CC);
    float* sq_ = sp_ + (size_t)SS * BB * CC;
    float* so_ = sq_ + (size_t)SS * BB * CC;
    unsigned short* woT = wT + (size_t)3 * CC * CC;
    unsigned short* srS = (unsigned short*)d_out;   // bf16 scratch inside out

    prep<<<dim3(256 + (MM * CC / 8) / 256), 256, 0, stream>>>(
        x, mk, mv, mr, wk, wv, wr, wo, wT, b1, b2, b3);

    gemm_kvr3<<<dim3(512, 3), 256, 0, stream>>>(wT, b1, b2, b3, b4, b5, srS);

    wkv_part1<<<dim3((SS * BB * CC) / 256), 256, 0, stream>>>(b4, b5, sd, sp_, sq_, so_);
    wkv_scan<<<dim3((BB * CC) / 2), 256, 0, stream>>>(sd, sp_, sq_, so_);
    wkv_part3<<<dim3((SS * BB * CC) / 256), 256, 0, stream>>>(
        b4, b5, srS, sd, sf, sp_, sq_, so_, b1);

    gemm_out<<<dim3(512), 256, 0, stream>>>(b1, woT, out);
}

// Round 6
// 296.152 us; speedup vs baseline: 1.0590x; 1.0123x over previous
//
#include <hip/hip_runtime.h>

// Problem constants (B=8, T=4096, C=512)
#define BB 8
#define TT 4096
#define CC 512
#define MM (BB * TT)   // 32768 rows
#define SS 128         // scan chunks
#define LL 32          // steps per chunk (SS*LL == TT)

typedef short short8 __attribute__((ext_vector_type(8)));
typedef unsigned short ushort8 __attribute__((ext_vector_type(8)));
typedef float f32x4 __attribute__((ext_vector_type(4)));

__device__ __forceinline__ unsigned short f2bf(float f) {
    unsigned int u = __float_as_uint(f);
    u += 0x7FFFu + ((u >> 16) & 1u);   // RNE
    return (unsigned short)(u >> 16);
}
__device__ __forceinline__ float bf2f(unsigned short h) {
    return __uint_as_float(((unsigned int)h) << 16);
}

// async global->LDS, 16B per lane. LDS dest must be wave-uniform base + lane*16.
__device__ __forceinline__ void gl_lds16(const void* g, void* l) {
    __builtin_amdgcn_global_load_lds(
        (__attribute__((address_space(1))) void*)(unsigned long long)g,
        (__attribute__((address_space(3))) void*)(unsigned int)(unsigned long long)l,
        16, 0, 0);
}

__device__ __forceinline__ ushort8 pack8(f32x4 a, f32x4 b) {
    ushort8 r;
    r[0] = f2bf(a.x); r[1] = f2bf(a.y); r[2] = f2bf(a.z); r[3] = f2bf(a.w);
    r[4] = f2bf(b.x); r[5] = f2bf(b.y); r[6] = f2bf(b.z); r[7] = f2bf(b.w);
    return r;
}

// ---------------------------------------------------------------------------
// Kernel 1: prep = weight transpose (blocks 0..255) + time-shift mix
// (blocks 256..8447) fused into one dispatch to cut a launch gap.
// ---------------------------------------------------------------------------
__global__ __launch_bounds__(256) void prep(
    const float* __restrict__ x,
    const float* __restrict__ mixk, const float* __restrict__ mixv,
    const float* __restrict__ mixr,
    const float* __restrict__ wk, const float* __restrict__ wv,
    const float* __restrict__ wr, const float* __restrict__ wo,
    unsigned short* __restrict__ wT,
    unsigned short* __restrict__ kx, unsigned short* __restrict__ vx,
    unsigned short* __restrict__ rx) {
    __shared__ float t[64][65];
    if (blockIdx.x < 256) {
        // ---- weight transpose: wT[n][k] = bf16(w[k][n]), LDS 64x64 tile ----
        const int bid = blockIdx.x;
        const int which = bid >> 6;
        const int rem = bid & 63;
        const int k0 = (rem >> 3) * 64;       // source row block
        const int n0 = (rem & 7) * 64;        // source col block
        const float* src = (which == 0) ? wk : (which == 1) ? wv
                         : (which == 2) ? wr : wo;
        const int r = threadIdx.x >> 6;       // 0..3
        const int c = threadIdx.x & 63;       // 0..63
#pragma unroll
        for (int p = 0; p < 16; ++p)
            t[p * 4 + r][c] = src[(size_t)(k0 + p * 4 + r) * CC + n0 + c];
        __syncthreads();
        unsigned short* dst = wT + (size_t)which * (CC * CC);
#pragma unroll
        for (int p = 0; p < 16; ++p)
            dst[(size_t)(n0 + p * 4 + r) * CC + k0 + c] = f2bf(t[c][p * 4 + r]);
        return;
    }
    // ---- time-shift mix for all three branches, one memory pass ----
    const int idx = (blockIdx.x - 256) * 256 + threadIdx.x;   // 0 .. MM*CC/8-1
    const int row = idx >> 6;
    const int ch  = (idx & 63) * 8;
    const int tt  = row & (TT - 1);
    const size_t off = (size_t)row * CC + ch;
    const float* xr = x + off;

    const f32x4 zero4 = {0.f, 0.f, 0.f, 0.f};
    const f32x4 one4  = {1.f, 1.f, 1.f, 1.f};

    f32x4 xc0 = ((const f32x4*)xr)[0];
    f32x4 xc1 = ((const f32x4*)xr)[1];
    f32x4 xp0 = zero4, xp1 = zero4;
    if (tt != 0) {
        xp0 = ((const f32x4*)(xr - CC))[0];
        xp1 = ((const f32x4*)(xr - CC))[1];
    }

    f32x4 m0, m1;
    m0 = ((const f32x4*)(mixk + ch))[0];
    m1 = ((const f32x4*)(mixk + ch))[1];
    *(ushort8*)(kx + off) = pack8(xc0 * m0 + xp0 * (one4 - m0),
                                  xc1 * m1 + xp1 * (one4 - m1));
    m0 = ((const f32x4*)(mixv + ch))[0];
    m1 = ((const f32x4*)(mixv + ch))[1];
    *(ushort8*)(vx + off) = pack8(xc0 * m0 + xp0 * (one4 - m0),
                                  xc1 * m1 + xp1 * (one4 - m1));
    m0 = ((const f32x4*)(mixr + ch))[0];
    m1 = ((const f32x4*)(mixr + ch))[1];
    *(ushort8*)(rx + off) = pack8(xc0 * m0 + xp0 * (one4 - m0),
                                  xc1 * m1 + xp1 * (one4 - m1));
}

// ---------------------------------------------------------------------------
// GEMM body: 128x256 tile, 3-deep LDS pipeline, counted vmcnt, raw barriers.
// Round-5/6 change vs the proven round-2 structure: the WAR drain
// (lgkmcnt(0) + barrier-B) moves AFTER the MFMA cluster. The MFMAs are
// ordered w.r.t. the ds_reads by SSA data deps, so the compiler is now free
// to interleave reads and MFMAs with its own counted lgkmcnt (m97 behavior),
// hiding ~576 cyc of LDS reads under ~620 cyc of MFMA per K-step.
// WAR chain still intact: reads retired (lgkmcnt(0)) before barrier-B, and
// the STG that overwrites this buffer issues only after barrier-B.
// Per K-step kt: STG(kt+2) | vmcnt(12) | barrier-A | ds_read+MFMA interleave
//                | lgkmcnt(0) | barrier-B
// LDS swizzle: 16B group g of row r at slot g ^ ((r>>1)&3) -> 2-way max
// (measured 0 bank conflicts).
// ---------------------------------------------------------------------------
template <bool F32OUT>
__device__ __forceinline__ void gemm_body(
    const unsigned short* __restrict__ A,
    const unsigned short* __restrict__ Bw,
    void* __restrict__ OutP, const int sig,
    const int pm, const int pn) {
    __shared__ unsigned short As[3][128 * 32];    // 3 x  8 KiB
    __shared__ unsigned short Bs[3][256 * 32];    // 3 x 16 KiB

    const int tid = threadIdx.x;
    const int ar = tid >> 2;                        // 0..63
    const int cg = (tid & 3) ^ ((tid >> 3) & 3);
    const unsigned short* agA = A  + (size_t)(pm * 128 + ar) * CC + cg * 8;
    const unsigned short* agB = Bw + (size_t)(pn * 256 + ar) * CC + cg * 8;

    const int w = tid >> 6, lane = tid & 63;
    const int wr = w >> 1, wc = w & 1;
    const int q = lane >> 4, l16 = lane & 15;
    const int sw = (q ^ ((l16 >> 1) & 3)) * 8;      // reader-side swizzle

    f32x4 acc[4][8];
#pragma unroll
    for (int i = 0; i < 4; i++)
#pragma unroll
        for (int j = 0; j < 8; j++) acc[i][j] = (f32x4){0.f, 0.f, 0.f, 0.f};

#define STG(bi, k0) do {                                                        \
    gl_lds16(agA + (k0), &As[bi][tid * 8]);                                     \
    gl_lds16(agA + (size_t)64 * CC + (k0), &As[bi][(256 + tid) * 8]);           \
    gl_lds16(agB + (k0),                    &Bs[bi][(0 * 256 + tid) * 8]);      \
    gl_lds16(agB + (size_t)64  * CC + (k0), &Bs[bi][(1 * 256 + tid) * 8]);      \
    gl_lds16(agB + (size_t)128 * CC + (k0), &Bs[bi][(2 * 256 + tid) * 8]);      \
    gl_lds16(agB + (size_t)192 * CC + (k0), &Bs[bi][(3 * 256 + tid) * 8]);      \
} while (0)

    STG(0, 0);
    STG(1, 32);

#pragma unroll
    for (int kt = 0; kt < 16; ++kt) {
        const int bi = kt % 3;                      // compile-time (unrolled)
        if (kt + 2 < 16) STG((kt + 2) % 3, (kt + 2) * 32);

        if (kt < 14)       asm volatile("s_waitcnt vmcnt(12)" ::: "memory");
        else if (kt == 14) asm volatile("s_waitcnt vmcnt(6)" ::: "memory");
        else               asm volatile("s_waitcnt vmcnt(0)" ::: "memory");
        __builtin_amdgcn_s_barrier();               // buf[bi] ready for all

        __builtin_amdgcn_s_setprio(1);
        short8 a[4], b[8];
#pragma unroll
        for (int i = 0; i < 4; i++)
            a[i] = *(const short8*)&As[bi][(wr * 64 + i * 16 + l16) * 32 + sw];
#pragma unroll
        for (int j = 0; j < 8; j++)
            b[j] = *(const short8*)&Bs[bi][(wc * 128 + j * 16 + l16) * 32 + sw];
        // no forced drain here: compiler interleaves MFMAs with counted lgkmcnt
#pragma unroll
        for (int i = 0; i < 4; i++)
#pragma unroll
            for (int j = 0; j < 8; j++)
                acc[i][j] = __builtin_amdgcn_mfma_f32_16x16x32_bf16(a[i], b[j], acc[i][j], 0, 0, 0);
        __builtin_amdgcn_s_setprio(0);

        asm volatile("s_waitcnt lgkmcnt(0)" ::: "memory");  // reads retired
        __builtin_amdgcn_s_barrier();               // WAR: safe to overwrite
    }
#undef STG

    // epilogue: row = wr*64 + i*16 + q*4 + ii, col = pn*256 + wc*128 + j*16 + l16
    const size_t rb = (size_t)pm * 128 + wr * 64;
    const int nb = pn * 256 + wc * 128;
    if constexpr (F32OUT) {
        float* Out = (float*)OutP;
#pragma unroll
        for (int i = 0; i < 4; i++)
#pragma unroll
            for (int j = 0; j < 8; j++)
#pragma unroll
                for (int ii = 0; ii < 4; ii++) {
                    const int m = i * 16 + q * 4 + ii;
                    const int n = nb + j * 16 + l16;
                    Out[(rb + m) * CC + n] = acc[i][j][ii];
                }
    } else {
        unsigned short* Out = (unsigned short*)OutP;
#pragma unroll
        for (int i = 0; i < 4; i++)
#pragma unroll
            for (int j = 0; j < 8; j++)
#pragma unroll
                for (int ii = 0; ii < 4; ii++) {
                    const int m = i * 16 + q * 4 + ii;
                    const int n = nb + j * 16 + l16;
                    float val = acc[i][j][ii];
                    if (sig) val = 1.0f / (1.0f + __expf(-val));
                    Out[(rb + m) * CC + n] = f2bf(val);
                }
    }
}

// ---------------------------------------------------------------------------
// Kernel 2: all three branch GEMMs in ONE dispatch.
// ---------------------------------------------------------------------------
__global__ __launch_bounds__(256, 2) void gemm_kvr3(
    const unsigned short* __restrict__ wT,
    const unsigned short* __restrict__ A0, const unsigned short* __restrict__ A1,
    const unsigned short* __restrict__ A2,
    unsigned short* __restrict__ O0, unsigned short* __restrict__ O1,
    unsigned short* __restrict__ O2) {
    const int z = blockIdx.y;
    const int lin = blockIdx.x;
    const int wg = (lin & 7) * 64 + (lin >> 3);
    const int pm = wg >> 1, pn = wg & 1;
    const unsigned short* A = (z == 0) ? A0 : (z == 1) ? A1 : A2;
    unsigned short* O = (z == 0) ? O0 : (z == 1) ? O1 : O2;
    gemm_body<false>(A, wT + (size_t)z * (CC * CC), O, z == 2, pm, pn);
}

// ---------------------------------------------------------------------------
// Kernel 3: out = z @ wo (fp32 output), same pipeline.
// ---------------------------------------------------------------------------
__global__ __launch_bounds__(256, 2) void gemm_out(
    const unsigned short* __restrict__ zb, const unsigned short* __restrict__ woT,
    float* __restrict__ out) {
    const int lin = blockIdx.x;
    const int wg = (lin & 7) * 64 + (lin >> 3);
    gemm_body<true>(zb, woT, out, 0, wg >> 1, wg & 1);
}

// ---------------------------------------------------------------------------
// WKV chunked parallel scan. part1 (per-chunk local states) unchanged.
// ---------------------------------------------------------------------------
__global__ __launch_bounds__(256) void wkv_part1(
    const unsigned short* __restrict__ kb, const unsigned short* __restrict__ vb,
    const float* __restrict__ sd,
    float* __restrict__ sp_, float* __restrict__ sq_, float* __restrict__ so_) {
    const int idx = blockIdx.x * 256 + threadIdx.x;
    const int c = idx & (CC - 1);
    const int b = (idx >> 9) & (BB - 1);
    const int s = idx >> 12;
    const float w = sd[c] * (1.0f / (float)TT);
    const size_t base = ((size_t)b * TT + (size_t)s * LL) * CC + c;
    const unsigned short* kp = kb + base;
    const unsigned short* vp = vb + base;

    float p = 0.f, q = 0.f, o = -1e38f;
#pragma unroll 8
    for (int i = 0; i < LL; ++i) {
        const float kt = bf2f(kp[(size_t)i * CC]);
        const float vt = bf2f(vp[(size_t)i * CC]);
        const float no2 = fmaxf(w + o, kt);
        const float A2  = __expf(w + o - no2);
        const float B2  = __expf(kt - no2);
        p = A2 * p + B2 * vt;
        q = A2 * q + B2;
        o = no2;
    }
    sp_[idx] = p; sq_[idx] = q; so_[idx] = o;
}

// ---------------------------------------------------------------------------
// wkv_scan: Hillis-Steele scan over the 128 chunk aggregates, in LDS, per
// (b,c) group. Combine is associative with per-step decay wL*2^d.
// In-place on sp_/sq_/so_; exclusive output (state BEFORE chunk s).
// ---------------------------------------------------------------------------
__global__ __launch_bounds__(256) void wkv_scan(
    const float* __restrict__ sd,
    float* __restrict__ sp_, float* __restrict__ sq_, float* __restrict__ so_) {
    __shared__ float P[2][128], Q[2][128], O[2][128];
    const int gsub = threadIdx.x >> 7;        // 0..1 (two groups per block)
    const int s    = threadIdx.x & 127;       // chunk index
    const int g    = blockIdx.x * 2 + gsub;   // 0..4095 = b*CC + c
    const int c    = g & (CC - 1);
    const float wL = sd[c] * ((float)LL / (float)TT);
    const int stride = BB * CC;               // 4096

    float p = sp_[s * stride + g];
    float q = sq_[s * stride + g];
    float o = so_[s * stride + g];
    P[gsub][s] = p; Q[gsub][s] = q; O[gsub][s] = o;

    float dec = wL;                            // wL * 2^d
#pragma unroll
    for (int d = 0; d < 7; ++d) {
        const int off = 1 << d;
        __syncthreads();
        float pl = 0.f, ql = 0.f, ol = -1e38f;
        if (s >= off) {
            pl = P[gsub][s - off]; ql = Q[gsub][s - off]; ol = O[gsub][s - off];
        }
        __syncthreads();
        if (s >= off) {
            // append own (right, 2^d chunks) after left aggregate
            const float no = fmaxf(ol + dec, o);
            const float Al = __expf(ol + dec - no);
            const float Bc = __expf(o - no);
            p = Al * pl + Bc * p;
            q = Al * ql + Bc * q;
            o = no;
            P[gsub][s] = p; Q[gsub][s] = q; O[gsub][s] = o;
        }
        dec += dec;
    }
    __syncthreads();
    // exclusive: state before chunk s (identity for s==0)
    float ep = 0.f, eq = 0.f, eo = -1e38f;
    if (s > 0) { ep = P[gsub][s - 1]; eq = Q[gsub][s - 1]; eo = O[gsub][s - 1]; }
    sp_[s * stride + g] = ep;
    sq_[s * stride + g] = eq;
    so_[s * stride + g] = eo;
}

__global__ __launch_bounds__(256) void wkv_part3(
    const unsigned short* __restrict__ kb, const unsigned short* __restrict__ vb,
    const unsigned short* __restrict__ srb,
    const float* __restrict__ sd, const float* __restrict__ sf,
    const float* __restrict__ sp_, const float* __restrict__ sq_,
    const float* __restrict__ so_,
    unsigned short* __restrict__ zb) {
    const int idx = blockIdx.x * 256 + threadIdx.x;
    const int c = idx & (CC - 1);
    const int b = (idx >> 9) & (BB - 1);
    const int s = idx >> 12;
    const float w = sd[c] * (1.0f / (float)TT);
    const float u = sf[c] * (1.0f / (float)TT);
    const size_t base = ((size_t)b * TT + (size_t)s * LL) * CC + c;
    const unsigned short* kp = kb + base;
    const unsigned short* vp = vb + base;
    const unsigned short* sp = srb + base;
    unsigned short* zp = zb + base;

    float p = sp_[idx], q = sq_[idx], o = so_[idx];
#pragma unroll 4
    for (int i = 0; i < LL; ++i) {
        const float kt = bf2f(kp[(size_t)i * CC]);
        const float vt = bf2f(vp[(size_t)i * CC]);
        const float sr = bf2f(sp[(size_t)i * CC]);

        const float no = fmaxf(o, u + kt);
        const float A  = __expf(o - no);
        const float Bt = __expf(u + kt - no);
        const float y  = (A * p + Bt * vt) / (A * q + Bt);
        zp[(size_t)i * CC] = f2bf(sr * y);

        const float no2 = fmaxf(w + o, kt);
        const float A2  = __expf(w + o - no2);
        const float B2  = __expf(kt - no2);
        p = A2 * p + B2 * vt;
        q = A2 * q + B2;
        o = no2;
    }
}

// ---------------------------------------------------------------------------
extern "C" void kernel_launch(void* const* d_in, const int* in_sizes, int n_in,
                              void* d_out, int out_size, void* d_ws, size_t ws_size,
                              hipStream_t stream) {
    const float* x  = (const float*)d_in[0];
    const float* sd = (const float*)d_in[1];
    const float* sf = (const float*)d_in[2];
    const float* mk = (const float*)d_in[3];
    const float* mv = (const float*)d_in[4];
    const float* mr = (const float*)d_in[5];
    const float* wk = (const float*)d_in[6];
    const float* wv = (const float*)d_in[7];
    const float* wr = (const float*)d_in[8];
    const float* wo = (const float*)d_in[9];
    float* out = (float*)d_out;

    // ws layout (168 MiB total; ws ceiling is in [194,200) MiB):
    //   wT     bf16 [4][512][512]  2 MiB
    //   b1..b5 bf16 [M][C]         5 x 32 MiB
    //   sp/sq/so fp32 [S][B][C]    3 x 2 MiB
    //
    // Rotation:
    //   prep: x -> b1 (xk), b2 (xv), b3 (xr); weights -> wT
    //   gemm: b1@wk -> b4 (k) ; b2@wv -> b5 (v) ; b3@wr -> srS=d_out (sr)
    //   wkv:  (b4, b5, srS) -> b1 (z)
    //   out:  b1 @ wo -> out (fp32, overwrites srS region)
    char* ws = (char*)d_ws;
    unsigned short* wT = (unsigned short*)ws;
    unsigned short* b1 = wT + (size_t)4 * CC * CC;
    unsigned short* b2 = b1 + (size_t)MM * CC;
    unsigned short* b3 = b2 + (size_t)MM * CC;
    unsigned short* b4 = b3 + (size_t)MM * CC;
    unsigned short* b5 = b4 + (size_t)MM * CC;
    float* sp_ = (float*)(b5 + (size_t)MM * CC);
    float* sq_ = sp_ + (size_t)SS * BB * CC;
    float* so_ = sq_ + (size_t)SS * BB * CC;
    unsigned short* woT = wT + (size_t)3 * CC * CC;
    unsigned short* srS = (unsigned short*)d_out;   // bf16 scratch inside out

    prep<<<dim3(256 + (MM * CC / 8) / 256), 256, 0, stream>>>(
        x, mk, mv, mr, wk, wv, wr, wo, wT, b1, b2, b3);

    gemm_kvr3<<<dim3(512, 3), 256, 0, stream>>>(wT, b1, b2, b3, b4, b5, srS);

    wkv_part1<<<dim3((SS * BB * CC) / 256), 256, 0, stream>>>(b4, b5, sd, sp_, sq_, so_);
    wkv_scan<<<dim3((BB * CC) / 2), 256, 0, stream>>>(sd, sp_, sq_, so_);
    wkv_part3<<<dim3((SS * BB * CC) / 256), 256, 0, stream>>>(
        b4, b5, srS, sd, sf, sp_, sq_, so_, b1);

    gemm_out<<<dim3(512), 256, 0, stream>>>(b1, woT, out);
}